// Round 1
// baseline (535.925 us; speedup 1.0000x reference)
//
#include <hip/hip_runtime.h>
#include <hip/hip_bf16.h>

#define B_ 8
#define K_ 8
#define H_ 256
#define W_ 256
#define HW (H_*W_)

// ---------------------------------------------------------------------------
// helpers
// ---------------------------------------------------------------------------
__device__ __forceinline__ unsigned short f2bf(float f) {
    __hip_bfloat16 h = __float2bfloat16(f);  // RNE
    return *reinterpret_cast<unsigned short*>(&h);
}
// unpack 8 bf16 (elem 2k in low 16 bits, 2k+1 in high) to f32
__device__ __forceinline__ void ub8(uint4 u, float* o) {
    o[0] = __uint_as_float(u.x << 16); o[1] = __uint_as_float(u.x & 0xffff0000u);
    o[2] = __uint_as_float(u.y << 16); o[3] = __uint_as_float(u.y & 0xffff0000u);
    o[4] = __uint_as_float(u.z << 16); o[5] = __uint_as_float(u.z & 0xffff0000u);
    o[6] = __uint_as_float(u.w << 16); o[7] = __uint_as_float(u.w & 0xffff0000u);
}
// sum within each 32-lane half of a wave; result valid in lanes 0 and 32
__device__ __forceinline__ float half_reduce(float v) {
    v += __shfl_down(v, 16, 64);
    v += __shfl_down(v, 8, 64);
    v += __shfl_down(v, 4, 64);
    v += __shfl_down(v, 2, 64);
    v += __shfl_down(v, 1, 64);
    return v;
}

// relaxed spin on an agent-scope counter (leader thread only)
__device__ __forceinline__ void wait_count(unsigned int* p, unsigned int target) {
    while (__hip_atomic_load(p, __ATOMIC_RELAXED, __HIP_MEMORY_SCOPE_AGENT) < target)
        __builtin_amdgcn_s_sleep(8);
}

// per-pixel warp + bilinear + residual; TG fragment comes from LDS (caller)
__device__ __forceinline__ void pixel_accum(
    const uint4* __restrict__ imgT,
    const uint4 t0, const uint4 g0, const uint4 g1,
    int b, int x, int y,
    float h00, float h01, float h02, float h10, float h11, float h12,
    float h20, float h21, float* aa) {
    const float X = (float)x - 127.5f, Y = (float)y - 127.5f;
    const float zw = h20 * X + h21 * Y + 1.f;
    const float Xw = (h00 * X + h01 * Y + h02) / zw + 127.5f;
    const float Yw = (h10 * X + h11 * Y + h12) / zw + 127.5f;
    const float NLO = -1.f + 2.f / 256.f, NHI = 1.f - 2.f / 256.f;
    const float xn = Xw / 127.5f - 1.f, yn = Yw / 127.5f - 1.f;
    const float m = (xn > NLO && xn < NHI && yn > NLO && yn < NHI) ? 1.f : 0.f;

    const float x0f = floorf(Xw), y0f = floorf(Yw);
    const float fx = Xw - x0f, fy = Yw - y0f;
    const float x1f = x0f + 1.f, y1f = y0f + 1.f;
    const bool vx0 = (x0f >= 0.f) && (x0f <= 255.f);
    const bool vx1 = (x1f >= 0.f) && (x1f <= 255.f);
    const bool vy0 = (y0f >= 0.f) && (y0f <= 255.f);
    const bool vy1 = (y1f >= 0.f) && (y1f <= 255.f);
    const int xi0 = (int)fminf(fmaxf(x0f, 0.f), 255.f);
    const int xi1 = (int)fminf(fmaxf(x1f, 0.f), 255.f);
    const int yi0 = (int)fminf(fmaxf(y0f, 0.f), 255.f);
    const int yi1 = (int)fminf(fmaxf(y1f, 0.f), 255.f);
    const int i00 = yi0 * W_ + xi0, i01 = yi0 * W_ + xi1;
    const int i10 = yi1 * W_ + xi0, i11 = yi1 * W_ + xi1;
    const float w00 = ((vx0 && vy0) ? 1.f : 0.f) * (1.f - fx) * (1.f - fy);
    const float w01 = ((vx1 && vy0) ? 1.f : 0.f) * fx * (1.f - fy);
    const float w10 = ((vx0 && vy1) ? 1.f : 0.f) * (1.f - fx) * fy;
    const float w11 = ((vx1 && vy1) ? 1.f : 0.f) * fx * fy;

    const int base = b * HW;
    const uint4 u00 = imgT[base + i00], u01 = imgT[base + i01];
    const uint4 u10 = imgT[base + i10], u11 = imgT[base + i11];

    float A00[8], A01[8], A10[8], A11[8], GXa[8], GYa[8], TV[8];
    ub8(u00, A00); ub8(u01, A01); ub8(u10, A10); ub8(u11, A11);
    ub8(t0, TV);   ub8(g0, GXa);  ub8(g1, GYa);

    float vx = 0.f, vy = 0.f;
    #pragma unroll
    for (int c = 0; c < 8; ++c) {
        const float Q = w00 * A00[c] + w01 * A01[c] + w10 * A10[c] + w11 * A11[c];
        const float r = Q - TV[c] * m;
        vx += GXa[c] * r;
        vy += GYa[c] * r;
    }
    const float t0a = X * vx, t4a = Y * vy;
    const float cc = t0a + t4a;
    aa[0] += t0a;      aa[1] += Y * vx;  aa[2] += vx;
    aa[3] += X * vy;   aa[4] += t4a;     aa[5] += vy;
    aa[6] -= X * cc;   aa[7] -= Y * cc;
}

// ---------------------------------------------------------------------------
// prep: transpose img/temp to channel-interleaved bf16 + grads; Gram via
// 15 row-moments. grid = B_*H_ blocks, 256 thr. Also zeroes the per-batch
// barrier counters used by the fused iteration kernel.
// ---------------------------------------------------------------------------
__global__ __launch_bounds__(256) void prep_kernel(
    const float* __restrict__ img, const float* __restrict__ temp,
    uint4* __restrict__ imgT, uint4* __restrict__ TG,
    double* __restrict__ gramP, unsigned int* __restrict__ bar) {
    __shared__ float smem[8192];
    __shared__ float s15[15];
    const int b   = blockIdx.x & 7;
    const int y   = blockIdx.x >> 3;
    const int tid = threadIdx.x;

    if (blockIdx.x < 8 && tid < 16)
        bar[(blockIdx.x * 16 + tid) * 32] = 0u;   // barrier counters for batch

    const int ym = (y > 0) ? y - 1 : 0;
    const int yp = (y < 255) ? y + 1 : 255;

    #pragma unroll
    for (int j = 0; j < 8; ++j) {
        const int slot = tid + 256 * j;
        const int rowid = slot >> 6, col4 = slot & 63;
        const int c = rowid >> 2, sel = rowid & 3;
        const int sy = (sel == 0) ? ym : ((sel == 2) ? yp : y);
        const float* src = ((sel == 3) ? img : temp)
                         + ((size_t)(b * K_ + c) * HW + sy * W_ + col4 * 4);
        const float4 v = *(const float4*)src;
        *(float4*)&smem[(c * 4 + sel) * 256 + col4 * 4] = v;
    }
    __syncthreads();

    const int x = tid;
    const int px = (y << 8) | x;
    const float X = (float)x - 127.5f, Y = (float)y - 127.5f;
    const int xm = (x > 0) ? x - 1 : 0;
    const int xp = (x < 255) ? x + 1 : 255;
    float Sxx = 0.f, Sxy = 0.f, Syy = 0.f;
    unsigned int imgp[4] = {0, 0, 0, 0};
    unsigned int tgp[12];
    #pragma unroll
    for (int i = 0; i < 12; ++i) tgp[i] = 0u;
    #pragma unroll
    for (int c = 0; c < 8; ++c) {
        const float* R = &smem[c * 1024];
        const float gx = 0.5f * (R[256 + xp] - R[256 + xm]);
        const float gy = 0.5f * (R[512 + x] - R[x]);
        const float tc = R[256 + x];
        const float iv = R[768 + x];
        Sxx += gx * gx; Sxy += gx * gy; Syy += gy * gy;
        const int sh = (c & 1) * 16;
        imgp[c >> 1]     |= ((unsigned int)f2bf(iv)) << sh;
        tgp[c >> 1]      |= ((unsigned int)f2bf(tc)) << sh;
        tgp[4 + (c >> 1)]|= ((unsigned int)f2bf(gx)) << sh;
        tgp[8 + (c >> 1)]|= ((unsigned int)f2bf(gy)) << sh;
    }
    const size_t gpx = (size_t)b * HW + px;
    imgT[gpx] = make_uint4(imgp[0], imgp[1], imgp[2], imgp[3]);
    uint4* tg = TG + gpx * 3;
    tg[0] = make_uint4(tgp[0], tgp[1], tgp[2],  tgp[3]);
    tg[1] = make_uint4(tgp[4], tgp[5], tgp[6],  tgp[7]);
    tg[2] = make_uint4(tgp[8], tgp[9], tgp[10], tgp[11]);
    __syncthreads();   // rows consumed; reuse smem for the moment reduce

    // ---- 15 row-moments: M[k*5+n] = sum_x S_k * X^n ----
    {
        const float X2 = X * X;
        const float Xp[5] = {1.f, X, X2, X2 * X, X2 * X2};
        #pragma unroll
        for (int n = 0; n < 5; ++n) {
            smem[n * 256 + tid]        = Sxx * Xp[n];
            smem[(5 + n) * 256 + tid]  = Sxy * Xp[n];
            smem[(10 + n) * 256 + tid] = Syy * Xp[n];
        }
    }
    __syncthreads();
    {
        const int e = tid >> 5, l = tid & 31;
        float v = 0.f;
        #pragma unroll
        for (int j = 0; j < 8; ++j) v += smem[e * 256 + l + 32 * j];
        v = half_reduce(v);
        if ((tid & 31) == 0) s15[e] = v;
    }
    if (tid < 224) {
        const int e = 8 + (tid >> 5), l = tid & 31;
        float v = 0.f;
        #pragma unroll
        for (int j = 0; j < 8; ++j) v += smem[e * 256 + l + 32 * j];
        v = half_reduce(v);
        if ((tid & 31) == 0) s15[e] = v;
    }
    __syncthreads();

    // ---- assemble 36 upper-tri entries from moments (f64) ----
    if (tid < 36) {
        const int aC[8]  = {1, 1, 1, 0, 0, 0, -1, -1};
        const int aNX[8] = {1, 0, 0, 0, 0, 0,  2,  1};
        const int aNY[8] = {0, 1, 0, 0, 0, 0,  0,  1};
        const int bC[8]  = {0, 0, 0, 1, 1, 1, -1, -1};
        const int bNX[8] = {0, 0, 0, 1, 0, 0,  1,  0};
        const int bNY[8] = {0, 0, 0, 0, 1, 0,  1,  2};
        const double Yd = (double)Y;
        const double Yp2 = Yd * Yd;
        const double Ypw[5] = {1.0, Yd, Yp2, Yp2 * Yd, Yp2 * Yp2};
        int p = 0, rem = tid;
        while (rem >= 8 - p) { rem -= 8 - p; ++p; }
        const int q = p + rem;
        double g = 0.0;
        const int ac = aC[p] * aC[q];
        if (ac) g += ac * Ypw[aNY[p] + aNY[q]] * (double)s15[aNX[p] + aNX[q]];
        const int ab1 = aC[p] * bC[q];
        if (ab1) g += ab1 * Ypw[aNY[p] + bNY[q]] * (double)s15[5 + aNX[p] + bNX[q]];
        const int ab2 = bC[p] * aC[q];
        if (ab2) g += ab2 * Ypw[bNY[p] + aNY[q]] * (double)s15[5 + bNX[p] + aNX[q]];
        const int bc = bC[p] * bC[q];
        if (bc) g += bc * Ypw[bNY[p] + bNY[q]] * (double)s15[10 + bNX[p] + bNX[q]];
        gramP[((size_t)b * 36 + tid) * 256 + y] = g;
    }
}

// ---------------------------------------------------------------------------
// fused: all 10 iterations + inversion + output in ONE persistent kernel.
// 512 blocks x 256 thr, 2 blocks/CU (LDS 58.8 KiB -> exactly 2 resident).
// Each block stages its 48 KiB TG slice into LDS once. Cross-block sync is a
// per-batch 64-block arrive/wait barrier (leader spin + agent fences); state
// (p, dp) chains redundantly-but-identically in LDS across iterations.
// Blocks 0..7 (yb==0, b==blockIdx) additionally run the Gram reduce + f64
// Gauss-Jordan inversion during iter 0 (invH first needed at iter 1).
// ---------------------------------------------------------------------------
__global__ __launch_bounds__(256, 2) void fused_kernel(
    const uint4* __restrict__ imgT, const uint4* __restrict__ TG,
    const double* __restrict__ gramP, double* __restrict__ invHg,
    const float* __restrict__ init_param,
    float* __restrict__ sP0, float* __restrict__ sP1,
    unsigned int* __restrict__ bar,
    const int* __restrict__ max_itr, float* __restrict__ out) {
    __shared__ uint4 sT[1024], sGX[1024], sGY[1024];   // 48 KiB TG slice
    __shared__ float red[2048];
    __shared__ float s8[8];
    __shared__ double sh_invH[64];
    __shared__ double sh_pd[16];     // p (0..7), dp (8..15) — persists per block
    __shared__ float sh_pf[8];
    __shared__ double gpart[144];
    __shared__ double shA[64], shB[64];

    const int tid = threadIdx.x;
    const int b   = blockIdx.x & 7;
    const int yb  = blockIdx.x >> 3;       // 0..63, rows 4*yb .. 4*yb+3
    const int mi_raw = *max_itr;
    const int mi = (mi_raw > 10) ? 10 : mi_raw;

    // ---- stage this block's TG slice (1024 px) into LDS, once ----
    {
        const size_t base = (size_t)b * HW + (size_t)yb * 1024;
        #pragma unroll
        for (int sub = 0; sub < 4; ++sub) {
            const int pxl = sub * 256 + tid;
            const uint4* tg = TG + (base + pxl) * 3;
            sT[pxl] = tg[0]; sGX[pxl] = tg[1]; sGY[pxl] = tg[2];
        }
    }
    __syncthreads();

    for (int it = 0; it < mi; ++it) {
        // ---- wait for previous iteration's partials (and invH after it 0) ----
        if (it > 0) {
            if (tid == 0) wait_count(&bar[(b * 16 + (it - 1)) * 32], 64u);
            __syncthreads();
            __builtin_amdgcn_fence(__ATOMIC_ACQUIRE, "agent");
            if (it == 1 && tid < 64) sh_invH[tid] = invHg[b * 64 + tid];

            // ---- state reconstruction (redundant per block, identical FP) ----
            const float* sR = ((it & 1) ? sP0 : sP1) + b * 512;
            const int e = tid >> 5, l = tid & 31;
            float v = sR[e * 64 + l] + sR[e * 64 + 32 + l];
            v = half_reduce(v);
            if ((tid & 31) == 0) s8[tid >> 5] = v;
            __syncthreads();
            if (tid < 8) {
                double nrm2 = 0.0;
                #pragma unroll
                for (int k2 = 0; k2 < 8; ++k2) {
                    const double d = sh_pd[8 + k2];
                    nrm2 += d * d;
                }
                double dpn = 0.0;
                if (tid < 6) {
                    #pragma unroll
                    for (int k2 = 0; k2 < 8; ++k2)
                        dpn += sh_invH[tid * 8 + k2] * (double)s8[k2];
                }
                const double dp2 = (sqrt(nrm2) > 1e-3) ? dpn : 0.0;
                const double pnew = sh_pd[tid] - dp2;   // reads precede writes (1 wave)
                sh_pd[tid]     = pnew;
                sh_pd[8 + tid] = dp2;
            }
            __syncthreads();
        } else {
            if (tid < 8) {
                sh_pd[tid]     = (double)init_param[b * 8 + tid];
                sh_pd[8 + tid] = 1.0;
            }
            __syncthreads();
        }

        const float h00 = 1.f + (float)sh_pd[0], h01 = (float)sh_pd[1], h02 = (float)sh_pd[2];
        const float h10 = (float)sh_pd[3], h11 = 1.f + (float)sh_pd[4], h12 = (float)sh_pd[5];
        const float h20 = (float)sh_pd[6], h21 = (float)sh_pd[7];

        // ---- pixel phase: 4 px/thread, TG from LDS, imgT gathers global ----
        float aa[8];
        #pragma unroll
        for (int e = 0; e < 8; ++e) aa[e] = 0.f;
        #pragma unroll 1
        for (int sub = 0; sub < 4; ++sub) {
            const int pxl = sub * 256 + tid;
            pixel_accum(imgT, sT[pxl], sGX[pxl], sGY[pxl], b, tid, yb * 4 + sub,
                        h00, h01, h02, h10, h11, h12, h20, h21, aa);
        }

        // ---- block reduce -> 8 partials per block ----
        #pragma unroll
        for (int e = 0; e < 8; ++e) red[e * 256 + tid] = aa[e];
        __syncthreads();
        {
            const int e = tid >> 5, l = tid & 31;
            float v = 0.f;
            #pragma unroll
            for (int j = 0; j < 8; ++j) v += red[e * 256 + l + 32 * j];
            v = half_reduce(v);
            if ((tid & 31) == 0) {
                float* sW = (it & 1) ? sP1 : sP0;
                sW[b * 512 + e * 64 + yb] = v;
            }
        }

        // ---- iter 0 only: blocks 0..7 run Gram reduce + inversion ----
        if (it == 0 && yb == 0) {
            if (tid < 144) {
                const int e = tid >> 2, q = tid & 3;
                const double* gp = gramP + ((size_t)b * 36 + e) * 256 + q * 64;
                double acc = 0.0;
                #pragma unroll 8
                for (int i = 0; i < 64; ++i) acc += gp[i];
                gpart[tid] = acc;
            }
            __syncthreads();
            const int i = tid >> 3, j = tid & 7;
            if (tid < 64) {
                const int pp = min(i, j), qq = max(i, j);
                const int tri = 8 * pp - (pp * (pp - 1)) / 2 + (qq - pp);
                shA[tid] = gpart[tri * 4] + gpart[tri * 4 + 1]
                         + gpart[tri * 4 + 2] + gpart[tri * 4 + 3];
                shB[tid] = (i == j) ? 1.0 : 0.0;
            }
            __syncthreads();
            for (int k = 0; k < 8; ++k) {
                const double piv = shA[k * 8 + k];
                __syncthreads();
                if (tid < 64 && i == k) { shA[tid] /= piv; shB[tid] /= piv; }
                __syncthreads();
                double f = 0, ak = 0, bk = 0;
                if (tid < 64) { f = shA[i * 8 + k]; ak = shA[k * 8 + j]; bk = shB[k * 8 + j]; }
                __syncthreads();
                if (tid < 64 && i != k) { shA[tid] -= f * ak; shB[tid] -= f * bk; }
                __syncthreads();
            }
            if (tid < 64) invHg[b * 64 + tid] = shB[tid];
        }

        // ---- arrive: make partials (+invHg) agent-visible, bump counter ----
        __syncthreads();                    // drains vmcnt per wave -> stores in L2
        if (tid == 0) {
            __threadfence();                // agent release (L2 wb)
            __hip_atomic_fetch_add(&bar[(b * 16 + it) * 32], 1u,
                                   __ATOMIC_RELEASE, __HIP_MEMORY_SCOPE_AGENT);
        }
    }

    // ---- output phase: blocks 0..7 (b == blockIdx) ----
    if (yb != 0) return;
    if (mi <= 0) {
        if (tid < 8) out[b * 8 + tid] = init_param[b * 8 + tid];
        if (tid < 9) {
            float v = (tid < 8) ? init_param[b * 8 + tid] : 0.f;
            if (tid == 0 || tid == 4 || tid == 8) v += 1.f;
            out[64 + b * 9 + tid] = v;
        }
        return;
    }
    if (tid == 0) wait_count(&bar[(b * 16 + (mi - 1)) * 32], 64u);
    __syncthreads();
    __builtin_amdgcn_fence(__ATOMIC_ACQUIRE, "agent");
    {
        const float* sb = (((mi - 1) & 1) ? sP1 : sP0) + b * 512;
        const int e = tid >> 5, l = tid & 31;
        float v = sb[e * 64 + l] + sb[e * 64 + 32 + l];
        v = half_reduce(v);
        if ((tid & 31) == 0) s8[tid >> 5] = v;
    }
    __syncthreads();
    if (tid < 8) {
        double nrm2 = 0.0;
        #pragma unroll
        for (int k2 = 0; k2 < 8; ++k2) {
            const double d = sh_pd[8 + k2];     // dp of last iteration (local chain)
            nrm2 += d * d;
        }
        double dpn = 0.0;
        if (tid < 6) {
            #pragma unroll
            for (int k2 = 0; k2 < 8; ++k2)
                dpn += invHg[b * 64 + tid * 8 + k2] * (double)s8[k2];
        }
        const double dp2 = (sqrt(nrm2) > 1e-3) ? dpn : 0.0;
        const float pf = (float)(sh_pd[tid] - dp2);
        sh_pf[tid] = pf;
        out[b * 8 + tid] = pf;
    }
    __syncthreads();
    if (tid < 9) {
        float v2 = (tid < 8) ? sh_pf[tid] : 0.f;
        if (tid == 0 || tid == 4 || tid == 8) v2 += 1.f;
        out[64 + b * 9 + tid] = v2;
    }
}

extern "C" void kernel_launch(void* const* d_in, const int* in_sizes, int n_in,
                              void* d_out, int out_size, void* d_ws, size_t ws_size,
                              hipStream_t stream) {
    const float* img        = (const float*)d_in[0];
    const float* temp       = (const float*)d_in[1];
    const float* init_param = (const float*)d_in[2];
    const int*   max_itr    = (const int*)d_in[3];
    float* out = (float*)d_out;

    char* w = (char*)d_ws;
    double* gramP = (double*)w;                       // 8*36*256 d = 576 KB
    double* invH  = gramP + 73728;                    // 512 d
    float*  sP0   = (float*)(invH + 512);             // 16 KB
    float*  sP1   = sP0 + 4096;                       // 16 KB
    unsigned int* bar = (unsigned int*)(sP1 + 4096);  // 16 KB barrier counters
    uint4* imgT   = (uint4*)(w + 1048576);            // 8.39 MB (bf16 x8 per px)
    uint4* TG     = (uint4*)(w + 1048576 + 8388608);  // 25.2 MB (T,gx,gy bf16 x8)

    prep_kernel<<<B_ * H_, 256, 0, stream>>>(img, temp, imgT, TG, gramP, bar);

    void* args[] = {(void*)&imgT, (void*)&TG, (void*)&gramP, (void*)&invH,
                    (void*)&init_param, (void*)&sP0, (void*)&sP1, (void*)&bar,
                    (void*)&max_itr, (void*)&out};
    hipError_t err = hipLaunchCooperativeKernel((void*)fused_kernel,
                                                dim3(512), dim3(256),
                                                args, 0, stream);
    if (err != hipSuccess) {
        // co-residency still holds by capacity: 58.8 KiB LDS -> exactly 2/CU,
        // 512 blocks == 256 CU x 2
        fused_kernel<<<512, 256, 0, stream>>>(imgT, TG, gramP, invH, init_param,
                                              sP0, sP1, bar, max_itr, out);
    }
}

// Round 3
// 186.410 us; speedup vs baseline: 2.8750x; 2.8750x over previous
//
#include <hip/hip_runtime.h>
#include <hip/hip_bf16.h>

#define B_ 8
#define K_ 8
#define H_ 256
#define W_ 256
#define HW (H_*W_)

// ---------------------------------------------------------------------------
// helpers
// ---------------------------------------------------------------------------
__device__ __forceinline__ unsigned short f2bf(float f) {
    __hip_bfloat16 h = __float2bfloat16(f);  // RNE
    return *reinterpret_cast<unsigned short*>(&h);
}
// unpack 8 bf16 (elem 2k in low 16 bits, 2k+1 in high) to f32
__device__ __forceinline__ void ub8(uint4 u, float* o) {
    o[0] = __uint_as_float(u.x << 16); o[1] = __uint_as_float(u.x & 0xffff0000u);
    o[2] = __uint_as_float(u.y << 16); o[3] = __uint_as_float(u.y & 0xffff0000u);
    o[4] = __uint_as_float(u.z << 16); o[5] = __uint_as_float(u.z & 0xffff0000u);
    o[6] = __uint_as_float(u.w << 16); o[7] = __uint_as_float(u.w & 0xffff0000u);
}
// sum within each 32-lane half of a wave; result valid in lanes 0 and 32
__device__ __forceinline__ float half_reduce(float v) {
    v += __shfl_down(v, 16, 64);
    v += __shfl_down(v, 8, 64);
    v += __shfl_down(v, 4, 64);
    v += __shfl_down(v, 2, 64);
    v += __shfl_down(v, 1, 64);
    return v;
}
// fine-grained coherent (cache-bypassing) accesses — NO L2 fences anywhere
__device__ __forceinline__ void cstore(float* p, float v) {
    __hip_atomic_store(p, v, __ATOMIC_RELAXED, __HIP_MEMORY_SCOPE_AGENT);
}
__device__ __forceinline__ float cload(const float* p) {
    return __hip_atomic_load((float*)p, __ATOMIC_RELAXED, __HIP_MEMORY_SCOPE_AGENT);
}
// BOUNDED relaxed spin on an agent-scope counter (leader thread only).
// Bound (~1e6 polls ≈ 1 s) never triggers when the barrier logic is correct
// (normal latency is µs); it converts a hypothetical deadlock into a
// wrong-answer-with-counters instead of a dead container.
__device__ __forceinline__ void wait_count(unsigned int* p, unsigned int target) {
    for (int i = 0; i < 1000000; ++i) {
        if (__hip_atomic_load(p, __ATOMIC_RELAXED, __HIP_MEMORY_SCOPE_AGENT) >= target)
            return;
        __builtin_amdgcn_s_sleep(1);
    }
}

// per-pixel warp + bilinear + residual; TG fragment comes from registers
__device__ __forceinline__ void pixel_accum(
    const uint4* __restrict__ imgT,
    const uint4 t0, const uint4 g0, const uint4 g1,
    int b, int x, int y,
    float h00, float h01, float h02, float h10, float h11, float h12,
    float h20, float h21, float* aa) {
    const float X = (float)x - 127.5f, Y = (float)y - 127.5f;
    const float zw = h20 * X + h21 * Y + 1.f;
    const float Xw = (h00 * X + h01 * Y + h02) / zw + 127.5f;
    const float Yw = (h10 * X + h11 * Y + h12) / zw + 127.5f;
    const float NLO = -1.f + 2.f / 256.f, NHI = 1.f - 2.f / 256.f;
    const float xn = Xw / 127.5f - 1.f, yn = Yw / 127.5f - 1.f;
    const float m = (xn > NLO && xn < NHI && yn > NLO && yn < NHI) ? 1.f : 0.f;

    const float x0f = floorf(Xw), y0f = floorf(Yw);
    const float fx = Xw - x0f, fy = Yw - y0f;
    const float x1f = x0f + 1.f, y1f = y0f + 1.f;
    const bool vx0 = (x0f >= 0.f) && (x0f <= 255.f);
    const bool vx1 = (x1f >= 0.f) && (x1f <= 255.f);
    const bool vy0 = (y0f >= 0.f) && (y0f <= 255.f);
    const bool vy1 = (y1f >= 0.f) && (y1f <= 255.f);
    const int xi0 = (int)fminf(fmaxf(x0f, 0.f), 255.f);
    const int xi1 = (int)fminf(fmaxf(x1f, 0.f), 255.f);
    const int yi0 = (int)fminf(fmaxf(y0f, 0.f), 255.f);
    const int yi1 = (int)fminf(fmaxf(y1f, 0.f), 255.f);
    const int i00 = yi0 * W_ + xi0, i01 = yi0 * W_ + xi1;
    const int i10 = yi1 * W_ + xi0, i11 = yi1 * W_ + xi1;
    const float w00 = ((vx0 && vy0) ? 1.f : 0.f) * (1.f - fx) * (1.f - fy);
    const float w01 = ((vx1 && vy0) ? 1.f : 0.f) * fx * (1.f - fy);
    const float w10 = ((vx0 && vy1) ? 1.f : 0.f) * (1.f - fx) * fy;
    const float w11 = ((vx1 && vy1) ? 1.f : 0.f) * fx * fy;

    const int base = b * HW;
    const uint4 u00 = imgT[base + i00], u01 = imgT[base + i01];
    const uint4 u10 = imgT[base + i10], u11 = imgT[base + i11];

    float A00[8], A01[8], A10[8], A11[8], GXa[8], GYa[8], TV[8];
    ub8(u00, A00); ub8(u01, A01); ub8(u10, A10); ub8(u11, A11);
    ub8(t0, TV);   ub8(g0, GXa);  ub8(g1, GYa);

    float vx = 0.f, vy = 0.f;
    #pragma unroll
    for (int c = 0; c < 8; ++c) {
        const float Q = w00 * A00[c] + w01 * A01[c] + w10 * A10[c] + w11 * A11[c];
        const float r = Q - TV[c] * m;
        vx += GXa[c] * r;
        vy += GYa[c] * r;
    }
    const float t0a = X * vx, t4a = Y * vy;
    const float cc = t0a + t4a;
    aa[0] += t0a;      aa[1] += Y * vx;  aa[2] += vx;
    aa[3] += X * vy;   aa[4] += t4a;     aa[5] += vy;
    aa[6] -= X * cc;   aa[7] -= Y * cc;
}

// ---------------------------------------------------------------------------
// prep: transpose img/temp to channel-interleaved bf16 + grads (PLANAR TG
// layout: T / GX / GY in separate arrays for coalesced access); Gram via 15
// row-moments. grid = B_*H_ blocks, 256 thr. Also zeroes barrier counters.
// ---------------------------------------------------------------------------
__global__ __launch_bounds__(256) void prep_kernel(
    const float* __restrict__ img, const float* __restrict__ temp,
    uint4* __restrict__ imgT, uint4* __restrict__ TGt,
    uint4* __restrict__ TGx, uint4* __restrict__ TGy,
    double* __restrict__ gramP, unsigned int* __restrict__ bar) {
    __shared__ float smem[8192];
    __shared__ float s15[15];
    const int b   = blockIdx.x & 7;
    const int y   = blockIdx.x >> 3;
    const int tid = threadIdx.x;

    if (blockIdx.x < 8 && tid < 16)
        bar[(blockIdx.x * 16 + tid) * 32] = 0u;   // barrier counters for batch

    const int ym = (y > 0) ? y - 1 : 0;
    const int yp = (y < 255) ? y + 1 : 255;

    #pragma unroll
    for (int j = 0; j < 8; ++j) {
        const int slot = tid + 256 * j;
        const int rowid = slot >> 6, col4 = slot & 63;
        const int c = rowid >> 2, sel = rowid & 3;
        const int sy = (sel == 0) ? ym : ((sel == 2) ? yp : y);
        const float* src = ((sel == 3) ? img : temp)
                         + ((size_t)(b * K_ + c) * HW + sy * W_ + col4 * 4);
        const float4 v = *(const float4*)src;
        *(float4*)&smem[(c * 4 + sel) * 256 + col4 * 4] = v;
    }
    __syncthreads();

    const int x = tid;
    const int px = (y << 8) | x;
    const float X = (float)x - 127.5f, Y = (float)y - 127.5f;
    const int xm = (x > 0) ? x - 1 : 0;
    const int xp = (x < 255) ? x + 1 : 255;
    float Sxx = 0.f, Sxy = 0.f, Syy = 0.f;
    unsigned int imgp[4] = {0, 0, 0, 0};
    unsigned int tgp[12];
    #pragma unroll
    for (int i = 0; i < 12; ++i) tgp[i] = 0u;
    #pragma unroll
    for (int c = 0; c < 8; ++c) {
        const float* R = &smem[c * 1024];
        const float gx = 0.5f * (R[256 + xp] - R[256 + xm]);
        const float gy = 0.5f * (R[512 + x] - R[x]);
        const float tc = R[256 + x];
        const float iv = R[768 + x];
        Sxx += gx * gx; Sxy += gx * gy; Syy += gy * gy;
        const int sh = (c & 1) * 16;
        imgp[c >> 1]     |= ((unsigned int)f2bf(iv)) << sh;
        tgp[c >> 1]      |= ((unsigned int)f2bf(tc)) << sh;
        tgp[4 + (c >> 1)]|= ((unsigned int)f2bf(gx)) << sh;
        tgp[8 + (c >> 1)]|= ((unsigned int)f2bf(gy)) << sh;
    }
    const size_t gpx = (size_t)b * HW + px;
    imgT[gpx] = make_uint4(imgp[0], imgp[1], imgp[2], imgp[3]);
    TGt[gpx] = make_uint4(tgp[0], tgp[1], tgp[2],  tgp[3]);
    TGx[gpx] = make_uint4(tgp[4], tgp[5], tgp[6],  tgp[7]);
    TGy[gpx] = make_uint4(tgp[8], tgp[9], tgp[10], tgp[11]);
    __syncthreads();   // rows consumed; reuse smem for the moment reduce

    // ---- 15 row-moments: M[k*5+n] = sum_x S_k * X^n ----
    {
        const float X2 = X * X;
        const float Xp[5] = {1.f, X, X2, X2 * X, X2 * X2};
        #pragma unroll
        for (int n = 0; n < 5; ++n) {
            smem[n * 256 + tid]        = Sxx * Xp[n];
            smem[(5 + n) * 256 + tid]  = Sxy * Xp[n];
            smem[(10 + n) * 256 + tid] = Syy * Xp[n];
        }
    }
    __syncthreads();
    {
        const int e = tid >> 5, l = tid & 31;
        float v = 0.f;
        #pragma unroll
        for (int j = 0; j < 8; ++j) v += smem[e * 256 + l + 32 * j];
        v = half_reduce(v);
        if ((tid & 31) == 0) s15[e] = v;
    }
    if (tid < 224) {
        const int e = 8 + (tid >> 5), l = tid & 31;
        float v = 0.f;
        #pragma unroll
        for (int j = 0; j < 8; ++j) v += smem[e * 256 + l + 32 * j];
        v = half_reduce(v);
        if ((tid & 31) == 0) s15[e] = v;
    }
    __syncthreads();

    // ---- assemble 36 upper-tri entries from moments (f64) ----
    if (tid < 36) {
        const int aC[8]  = {1, 1, 1, 0, 0, 0, -1, -1};
        const int aNX[8] = {1, 0, 0, 0, 0, 0,  2,  1};
        const int aNY[8] = {0, 1, 0, 0, 0, 0,  0,  1};
        const int bC[8]  = {0, 0, 0, 1, 1, 1, -1, -1};
        const int bNX[8] = {0, 0, 0, 1, 0, 0,  1,  0};
        const int bNY[8] = {0, 0, 0, 0, 1, 0,  1,  2};
        const double Yd = (double)Y;
        const double Yp2 = Yd * Yd;
        const double Ypw[5] = {1.0, Yd, Yp2, Yp2 * Yd, Yp2 * Yp2};
        int p = 0, rem = tid;
        while (rem >= 8 - p) { rem -= 8 - p; ++p; }
        const int q = p + rem;
        double g = 0.0;
        const int ac = aC[p] * aC[q];
        if (ac) g += ac * Ypw[aNY[p] + aNY[q]] * (double)s15[aNX[p] + aNX[q]];
        const int ab1 = aC[p] * bC[q];
        if (ab1) g += ab1 * Ypw[aNY[p] + bNY[q]] * (double)s15[5 + aNX[p] + bNX[q]];
        const int ab2 = bC[p] * aC[q];
        if (ab2) g += ab2 * Ypw[bNY[p] + aNY[q]] * (double)s15[5 + bNX[p] + aNX[q]];
        const int bc = bC[p] * bC[q];
        if (bc) g += bc * Ypw[bNY[p] + bNY[q]] * (double)s15[10 + bNX[p] + bNX[q]];
        gramP[((size_t)b * 36 + tid) * 256 + y] = g;
    }
}

// ---------------------------------------------------------------------------
// fused: all 10 iterations + inversion + output in ONE persistent kernel.
// 512 blocks x 256 thr (2 blocks/CU by grid). TG slice lives in REGISTERS.
// Cross-block sync: per-batch 64-block arrive/wait via fine-grained coherent
// (cache-bypassing) atomics — NO agent fences, NO buffer_wbl2/buffer_inv, so
// L2 stays warm with imgT across iterations. Every block redundantly computes
// the 8x8 Gram inversion from gramP during the iter-0 barrier window
// (identical FP order -> bit-identical invH in every block).
// ---------------------------------------------------------------------------
__global__ __launch_bounds__(256, 2) void fused_kernel(
    const uint4* __restrict__ imgT,
    const uint4* __restrict__ TGt, const uint4* __restrict__ TGx,
    const uint4* __restrict__ TGy,
    const double* __restrict__ gramP,
    const float* __restrict__ init_param,
    float* __restrict__ sP0, float* __restrict__ sP1,
    unsigned int* __restrict__ bar,
    const int* __restrict__ max_itr, float* __restrict__ out) {
    __shared__ float red[2048];
    __shared__ float s8[8];
    __shared__ double sh_invH[64];
    __shared__ double sh_pd[16];     // p (0..7), dp (8..15) — persists per block
    __shared__ float sh_pf[8];
    __shared__ double gpart[144];
    __shared__ double shA[64], shB[64];

    const int tid = threadIdx.x;
    const int b   = blockIdx.x & 7;
    const int yb  = blockIdx.x >> 3;       // 0..63, rows 4*yb .. 4*yb+3
    const int mi_raw = *max_itr;
    const int mi = (mi_raw > 10) ? 10 : mi_raw;

    // ---- TG slice into registers (each thread keeps its own 4 pixels) ----
    uint4 rT[4], rGX[4], rGY[4];
    {
        const size_t base = (size_t)b * HW + (size_t)yb * 1024 + tid;
        #pragma unroll
        for (int sub = 0; sub < 4; ++sub) {
            const size_t px = base + (size_t)(sub * 256);
            rT[sub] = TGt[px]; rGX[sub] = TGx[px]; rGY[sub] = TGy[px];
        }
    }

    for (int it = 0; it < mi; ++it) {
        if (it > 0) {
            // ---- wait for previous iteration's partials ----
            if (tid == 0) wait_count(&bar[(b * 16 + (it - 1)) * 32], 64u);
            __syncthreads();
            // ---- state reconstruction (coherent reads; identical FP/block) ----
            const float* sR = ((it & 1) ? sP0 : sP1) + b * 512;
            const int e = tid >> 5, l = tid & 31;
            float v = cload(&sR[e * 64 + l]) + cload(&sR[e * 64 + 32 + l]);
            v = half_reduce(v);
            if ((tid & 31) == 0) s8[tid >> 5] = v;
            __syncthreads();
            if (tid < 8) {
                double nrm2 = 0.0;
                #pragma unroll
                for (int k2 = 0; k2 < 8; ++k2) {
                    const double d = sh_pd[8 + k2];
                    nrm2 += d * d;
                }
                double dpn = 0.0;
                if (tid < 6) {
                    #pragma unroll
                    for (int k2 = 0; k2 < 8; ++k2)
                        dpn += sh_invH[tid * 8 + k2] * (double)s8[k2];
                }
                const double dp2 = (sqrt(nrm2) > 1e-3) ? dpn : 0.0;
                const double pnew = sh_pd[tid] - dp2;   // reads precede writes (1 wave)
                sh_pd[tid]     = pnew;
                sh_pd[8 + tid] = dp2;
            }
            __syncthreads();
        } else {
            if (tid < 8) {
                sh_pd[tid]     = (double)init_param[b * 8 + tid];
                sh_pd[8 + tid] = 1.0;
            }
            __syncthreads();
        }

        const float h00 = 1.f + (float)sh_pd[0], h01 = (float)sh_pd[1], h02 = (float)sh_pd[2];
        const float h10 = (float)sh_pd[3], h11 = 1.f + (float)sh_pd[4], h12 = (float)sh_pd[5];
        const float h20 = (float)sh_pd[6], h21 = (float)sh_pd[7];

        // ---- pixel phase: 4 px/thread fully unrolled (16 gathers in flight) ----
        float aa[8];
        #pragma unroll
        for (int e = 0; e < 8; ++e) aa[e] = 0.f;
        #pragma unroll
        for (int sub = 0; sub < 4; ++sub) {
            pixel_accum(imgT, rT[sub], rGX[sub], rGY[sub], b, tid, yb * 4 + sub,
                        h00, h01, h02, h10, h11, h12, h20, h21, aa);
        }

        // ---- block reduce -> 8 coherent partial stores per block ----
        #pragma unroll
        for (int e = 0; e < 8; ++e) red[e * 256 + tid] = aa[e];
        __syncthreads();
        {
            const int e = tid >> 5, l = tid & 31;
            float v = 0.f;
            #pragma unroll
            for (int j = 0; j < 8; ++j) v += red[e * 256 + l + 32 * j];
            v = half_reduce(v);
            if ((tid & 31) == 0) {
                float* sW = (it & 1) ? sP1 : sP0;
                cstore(&sW[b * 512 + e * 64 + yb], v);
            }
        }

        // ---- arrive: drain write-through stores, then bump counter ----
        asm volatile("s_waitcnt vmcnt(0)" ::: "memory");
        __syncthreads();
        if (tid == 0)
            __hip_atomic_fetch_add(&bar[(b * 16 + it) * 32], 1u,
                                   __ATOMIC_RELAXED, __HIP_MEMORY_SCOPE_AGENT);

        // ---- iter 0 only: EVERY block computes invH redundantly (hidden in
        //      the iter-0 barrier window; identical order -> identical bits) ----
        if (it == 0) {
            if (tid < 144) {
                const int e = tid >> 2, q = tid & 3;
                const double* gp = gramP + ((size_t)b * 36 + e) * 256 + q * 64;
                double acc = 0.0;
                #pragma unroll 8
                for (int i = 0; i < 64; ++i) acc += gp[i];
                gpart[tid] = acc;
            }
            __syncthreads();
            const int i = tid >> 3, j = tid & 7;
            if (tid < 64) {
                const int pp = min(i, j), qq = max(i, j);
                const int tri = 8 * pp - (pp * (pp - 1)) / 2 + (qq - pp);
                shA[tid] = gpart[tri * 4] + gpart[tri * 4 + 1]
                         + gpart[tri * 4 + 2] + gpart[tri * 4 + 3];
                shB[tid] = (i == j) ? 1.0 : 0.0;
            }
            __syncthreads();
            for (int k = 0; k < 8; ++k) {
                const double piv = shA[k * 8 + k];
                __syncthreads();
                if (tid < 64 && i == k) { shA[tid] /= piv; shB[tid] /= piv; }
                __syncthreads();
                double f = 0, ak = 0, bk = 0;
                if (tid < 64) { f = shA[i * 8 + k]; ak = shA[k * 8 + j]; bk = shB[k * 8 + j]; }
                __syncthreads();
                if (tid < 64 && i != k) { shA[tid] -= f * ak; shB[tid] -= f * bk; }
                __syncthreads();
            }
            if (tid < 64) sh_invH[tid] = shB[tid];
            __syncthreads();
        }
    }

    // ---- output phase: blocks 0..7 (b == blockIdx) ----
    if (yb != 0) return;
    if (mi <= 0) {
        if (tid < 8) out[b * 8 + tid] = init_param[b * 8 + tid];
        if (tid < 9) {
            float v = (tid < 8) ? init_param[b * 8 + tid] : 0.f;
            if (tid == 0 || tid == 4 || tid == 8) v += 1.f;
            out[64 + b * 9 + tid] = v;
        }
        return;
    }
    if (tid == 0) wait_count(&bar[(b * 16 + (mi - 1)) * 32], 64u);
    __syncthreads();
    {
        const float* sb = (((mi - 1) & 1) ? sP1 : sP0) + b * 512;
        const int e = tid >> 5, l = tid & 31;
        float v = cload(&sb[e * 64 + l]) + cload(&sb[e * 64 + 32 + l]);
        v = half_reduce(v);
        if ((tid & 31) == 0) s8[tid >> 5] = v;
    }
    __syncthreads();
    if (tid < 8) {
        double nrm2 = 0.0;
        #pragma unroll
        for (int k2 = 0; k2 < 8; ++k2) {
            const double d = sh_pd[8 + k2];     // dp of last iteration (local chain)
            nrm2 += d * d;
        }
        double dpn = 0.0;
        if (tid < 6) {
            #pragma unroll
            for (int k2 = 0; k2 < 8; ++k2)
                dpn += sh_invH[tid * 8 + k2] * (double)s8[k2];
        }
        const double dp2 = (sqrt(nrm2) > 1e-3) ? dpn : 0.0;
        const float pf = (float)(sh_pd[tid] - dp2);
        sh_pf[tid] = pf;
        out[b * 8 + tid] = pf;
    }
    __syncthreads();
    if (tid < 9) {
        float v2 = (tid < 8) ? sh_pf[tid] : 0.f;
        if (tid == 0 || tid == 4 || tid == 8) v2 += 1.f;
        out[64 + b * 9 + tid] = v2;
    }
}

extern "C" void kernel_launch(void* const* d_in, const int* in_sizes, int n_in,
                              void* d_out, int out_size, void* d_ws, size_t ws_size,
                              hipStream_t stream) {
    const float* img        = (const float*)d_in[0];
    const float* temp       = (const float*)d_in[1];
    const float* init_param = (const float*)d_in[2];
    const int*   max_itr    = (const int*)d_in[3];
    float* out = (float*)d_out;

    char* w = (char*)d_ws;
    double* gramP = (double*)w;                       // 8*36*256 d = 576 KB
    float*  sP0   = (float*)(gramP + 73728);          // 16 KB
    float*  sP1   = sP0 + 4096;                       // 16 KB
    unsigned int* bar = (unsigned int*)(sP1 + 4096);  // 16 KB barrier counters
    uint4* imgT   = (uint4*)(w + 1048576);            // 8.39 MB (bf16 x8 per px)
    uint4* TGt    = (uint4*)(w + 1048576 + 8388608);  // planar T / GX / GY
    uint4* TGx    = TGt + (size_t)B_ * HW;
    uint4* TGy    = TGx + (size_t)B_ * HW;

    prep_kernel<<<B_ * H_, 256, 0, stream>>>(img, temp, imgT, TGt, TGx, TGy,
                                             gramP, bar);

    void* args[] = {(void*)&imgT, (void*)&TGt, (void*)&TGx, (void*)&TGy,
                    (void*)&gramP, (void*)&init_param, (void*)&sP0, (void*)&sP1,
                    (void*)&bar, (void*)&max_itr, (void*)&out};
    hipError_t err = hipLaunchCooperativeKernel((void*)fused_kernel,
                                                dim3(512), dim3(256),
                                                args, 0, stream);
    if (err != hipSuccess) {
        // co-residency by capacity: 512 blocks == 256 CU x 2 (grid-limited)
        fused_kernel<<<512, 256, 0, stream>>>(imgT, TGt, TGx, TGy, gramP,
                                              init_param, sP0, sP1, bar,
                                              max_itr, out);
    }
}